// Round 1
// baseline (1641.273 us; speedup 1.0000x reference)
//
#include <hip/hip_runtime.h>
#include <hip/hip_bf16.h>
#include <math.h>

#define N_TOK 131072
#define DIM 256
#define HID 512
#define NE 16
#define CAP 18023

typedef __bf16 bf16_t;
typedef __bf16 bf16x4 __attribute__((ext_vector_type(4)));
typedef __bf16 bf16x8 __attribute__((ext_vector_type(8)));
typedef float floatx4 __attribute__((ext_vector_type(4)));

// ---------------------------------------------------------------------------
// Workspace layout (bytes):
//   0       : int   cnt[16]
//   64      : float imp[16]          (importance sums)
//   128     : float ent[1]           (entropy sum)
//   256     : int   tok_list[16*CAP] (1153472 B)
//   1153728 : float sc_list[16*CAP]  (1153472 B)
//   2359296 : bf16  W1T[16][512][256] (4 MiB)   W1T[e][n][k] = W1[e][k][n]
//   6553600 : bf16  W2T[16][256][512] (4 MiB)   W2T[e][d][h] = W2[e][h][d]
// total ~10.25 MiB
// ---------------------------------------------------------------------------
#define OFF_CNT 0
#define OFF_IMP 64
#define OFF_ENT 128
#define OFF_TOK 256
#define OFF_SC 1153728
#define OFF_W1T 2359296
#define OFF_W2T 6553600

// ---------------- zero output + stats ----------------
__global__ void k_zero(float* __restrict__ out, int* __restrict__ cnt,
                       float* __restrict__ imp, float* __restrict__ ent) {
  const int nthreads = 2048 * 256;  // grid is 2048 x 256
  int tid = blockIdx.x * 256 + threadIdx.x;
  float4* o4 = (float4*)out;
  float4 z = make_float4(0.f, 0.f, 0.f, 0.f);
#pragma unroll
  for (int j = 0; j < 16; j++) o4[(size_t)j * nthreads + tid] = z;  // 16*524288*4 = N*DIM
  if (blockIdx.x == 0) {
    if (threadIdx.x < NE) { cnt[threadIdx.x] = 0; imp[threadIdx.x] = 0.f; }
    if (threadIdx.x == NE) ent[0] = 0.f;
  }
}

// ---------------- per-expert weight transpose + bf16 cast ----------------
// src: [E][R][C] f32 -> dst: [E][C][R] bf16
__global__ void k_transpose(const float* __restrict__ src, bf16_t* __restrict__ dst,
                            int R, int C) {
  __shared__ float tile[32][33];
  int e = blockIdx.z;
  int c0 = blockIdx.x * 32;
  int r0 = blockIdx.y * 32;
  const float* s = src + (size_t)e * R * C;
  bf16_t* d = dst + (size_t)e * R * C;
  int tx = threadIdx.x, ty = threadIdx.y;  // block (32,8)
#pragma unroll
  for (int i = 0; i < 4; i++)
    tile[ty + i * 8][tx] = s[(size_t)(r0 + ty + i * 8) * C + (c0 + tx)];
  __syncthreads();
#pragma unroll
  for (int i = 0; i < 4; i++)
    d[(size_t)(c0 + ty + i * 8) * R + (r0 + tx)] = (bf16_t)tile[tx][ty + i * 8];
}

// ---------------- router: fp64 logits, top-2, gates, stats ----------------
__launch_bounds__(256, 2)
__global__ void k_router(const float* __restrict__ ctx, const float* __restrict__ Wg,
                         const float* __restrict__ bg, int* __restrict__ cnt,
                         int* __restrict__ tok_list, float* __restrict__ sc_list,
                         float* __restrict__ imp, float* __restrict__ ent) {
  __shared__ double wg64[DIM * NE];  // 32 KiB, Wg in fp64
  __shared__ float xt[256 * 33];     // 33 KiB, 256 tokens x 32-dim chunk, stride 33 (bank-safe)
  const int tid = threadIdx.x;
  const int tok0 = blockIdx.x * 256;

  for (int i = 0; i < 16; i++) {
    int idx = i * 256 + tid;
    wg64[idx] = (double)Wg[idx];
  }

  double acc[NE];
#pragma unroll
  for (int e = 0; e < NE; e++) acc[e] = (double)bg[e];

  for (int c = 0; c < 8; c++) {
    __syncthreads();  // also orders wg64 load before first compute
    const float* src = ctx + (size_t)tok0 * DIM + c * 32;
#pragma unroll
    for (int i = 0; i < 8; i++) {
      int f = i * 256 + tid;  // float4 index within tile
      int row = f >> 3;
      int c4 = f & 7;
      float4 v = *(const float4*)(src + (size_t)row * DIM + c4 * 4);
      float* dstp = &xt[row * 33 + c4 * 4];
      dstp[0] = v.x; dstp[1] = v.y; dstp[2] = v.z; dstp[3] = v.w;
    }
    __syncthreads();
#pragma unroll
    for (int d = 0; d < 32; d++) {
      double x = (double)xt[tid * 33 + d];
      const double* wrow = &wg64[(c * 32 + d) * NE];
#pragma unroll
      for (int e = 0; e < NE; e++) acc[e] = fma(x, wrow[e], acc[e]);
    }
  }

  // top-2 (strict >: ties keep lowest index, matches lax.top_k)
  double v1 = -1e300, v2 = -1e300;
  int i1 = 0, i2 = 0;
#pragma unroll
  for (int e = 0; e < NE; e++) {
    double v = acc[e];
    if (v > v1) { v2 = v1; i2 = i1; v1 = v; i1 = e; }
    else if (v > v2) { v2 = v; i2 = e; }
  }

  // softmax probs (f32 ok: feeds only importance/entropy, 2% thresholds)
  float p[NE];
  float s = 0.f;
#pragma unroll
  for (int e = 0; e < NE; e++) { p[e] = expf((float)(acc[e] - v1)); s += p[e]; }
  float inv = 1.f / s;
  float entl = 0.f;
#pragma unroll
  for (int e = 0; e < NE; e++) {
    float pe = p[e] * inv; p[e] = pe;
    entl -= pe * logf(fmaxf(pe, 1e-9f));
  }

  // gate scores: softmax over top-2 values, fp64
  double rr = exp(v2 - v1);
  double den = 1.0 + rr;
  float g1 = (float)(1.0 / den);
  float g2 = (float)(rr / den);

  int token = tok0 + tid;
  int pos = atomicAdd(&cnt[i1], 1);
  if (pos < CAP) { tok_list[i1 * CAP + pos] = token; sc_list[i1 * CAP + pos] = g1; }
  pos = atomicAdd(&cnt[i2], 1);
  if (pos < CAP) { tok_list[i2 * CAP + pos] = token; sc_list[i2 * CAP + pos] = g2; }

  // wave-reduce importance + entropy, one atomic per wave
#pragma unroll
  for (int e = 0; e < NE; e++) {
    float v = p[e];
#pragma unroll
    for (int o = 32; o > 0; o >>= 1) v += __shfl_down(v, o);
    if ((tid & 63) == 0) atomicAdd(&imp[e], v);
  }
  {
    float v = entl;
#pragma unroll
    for (int o = 32; o > 0; o >>= 1) v += __shfl_down(v, o);
    if ((tid & 63) == 0) atomicAdd(ent, v);
  }
}

// ---------------- fused 2-layer expert MLP, 64-slot tile, bf16 MFMA ----------------
#define XB_STRIDE 264  // 256 + 8 bf16 pad (16B) -> ~2-way LDS banks on b128 reads
#define HB_STRIDE 520  // 512 + 8

__launch_bounds__(256, 2)
__global__ void k_expert(const float* __restrict__ ctx,
                         const bf16_t* __restrict__ W1T, const float* __restrict__ b1,
                         const bf16_t* __restrict__ W2T, const float* __restrict__ b2,
                         const int* __restrict__ cnt,
                         const int* __restrict__ tok_list, const float* __restrict__ sc_list,
                         float* __restrict__ out) {
  // xb [64][264] bf16 (33792 B) aliases hb [64][520] bf16 (66560 B) — xb dead after GEMM1
  __shared__ __align__(16) char smem_raw[64 * HB_STRIDE * 2];
  __shared__ int tok_s[64];
  __shared__ float sc_s[64];
  __shared__ float b1s[HID];
  __shared__ float b2s[DIM];
  bf16_t* xb = (bf16_t*)smem_raw;
  bf16_t* hb = (bf16_t*)smem_raw;

  // XCD swizzle: bid%8 -> XCD; each XCD serves experts {2x, 2x+1} so its 1MB of
  // bf16 weights stays resident in that XCD's 4MB L2.
  const int bid = blockIdx.x;
  const int e = (bid & 7) * 2 + ((bid >> 3) & 1);
  const int chunk = bid >> 4;

  const int count = min(cnt[e], CAP);
  const int m0 = chunk * 64;
  if (m0 >= count) return;  // uniform early-exit, before any barrier
  const int rem = min(64, count - m0);

  const int tid = threadIdx.x;
  const int lane = tid & 63;
  const int w = tid >> 6;       // wave 0..3
  const int L15 = lane & 15;
  const int quad = lane >> 4;

  if (tid < 64) {
    int t = 0; float sgate = 0.f;  // padded slots: token 0, gate 0 -> adds exact 0
    if (tid < rem) {
      t = tok_list[e * CAP + m0 + tid];
      sgate = sc_list[e * CAP + m0 + tid];
    }
    tok_s[tid] = t; sc_s[tid] = sgate;
  }
  for (int i = tid; i < HID; i += 256) b1s[i] = b1[e * HID + i];
  for (int i = tid; i < DIM; i += 256) b2s[i] = b2[e * DIM + i];
  __syncthreads();

  // gather x: one full 1KB context row per wave-instr (coalesced), cast bf16
#pragma unroll
  for (int i = 0; i < 16; i++) {
    int f = i * 256 + tid;
    int row = f >> 6;   // wave-uniform
    int c4 = f & 63;    // = lane
    float4 v = *(const float4*)(ctx + (size_t)tok_s[row] * DIM + c4 * 4);
    bf16x4 bv;
    bv[0] = (bf16_t)v.x; bv[1] = (bf16_t)v.y; bv[2] = (bf16_t)v.z; bv[3] = (bf16_t)v.w;
    *(bf16x4*)(xb + row * XB_STRIDE + c4 * 4) = bv;
  }
  __syncthreads();

  // ---- GEMM1': hT[n][m] = sum_k W1T[n][k] * x[m][k]; wave w owns n in [w*128, w*128+128)
  // A-frag = W1T rows (global, K-contig); B-frag = xb rows (LDS, K-contig).
  floatx4 acc1[8][4];
#pragma unroll
  for (int it = 0; it < 8; it++)
#pragma unroll
    for (int jt = 0; jt < 4; jt++) {
      floatx4 z = {0.f, 0.f, 0.f, 0.f};
      acc1[it][jt] = z;
    }

  const bf16_t* w1e = W1T + (size_t)e * HID * DIM;
#pragma unroll
  for (int k = 0; k < 8; k++) {
    bf16x8 afr[8];
#pragma unroll
    for (int it = 0; it < 8; it++) {
      int n = w * 128 + it * 16 + L15;
      afr[it] = *(const bf16x8*)(w1e + n * DIM + k * 32 + quad * 8);
    }
    bf16x8 bfr[4];
#pragma unroll
    for (int jt = 0; jt < 4; jt++) {
      int m = jt * 16 + L15;
      bfr[jt] = *(const bf16x8*)(xb + m * XB_STRIDE + k * 32 + quad * 8);
    }
#pragma unroll
    for (int it = 0; it < 8; it++)
#pragma unroll
      for (int jt = 0; jt < 4; jt++)
        acc1[it][jt] = __builtin_amdgcn_mfma_f32_16x16x32_bf16(afr[it], bfr[jt],
                                                               acc1[it][jt], 0, 0, 0);
  }
  __syncthreads();  // everyone done reading xb; hb may now overwrite it

  // epilogue 1: D[i=quad*4+r][j=L15] = hT[n0+r][m] -> h[m][n]; 4 consecutive n per
  // lane -> packed ds_write_b64 into hb[m][n] (A-operand-ready for GEMM2)
#pragma unroll
  for (int it = 0; it < 8; it++) {
    int n0 = w * 128 + it * 16 + quad * 4;
    float4 bb = *(const float4*)(&b1s[n0]);
#pragma unroll
    for (int jt = 0; jt < 4; jt++) {
      int m = jt * 16 + L15;
      bf16x4 hv;
      hv[0] = (bf16_t)fmaxf(acc1[it][jt][0] + bb.x, 0.f);
      hv[1] = (bf16_t)fmaxf(acc1[it][jt][1] + bb.y, 0.f);
      hv[2] = (bf16_t)fmaxf(acc1[it][jt][2] + bb.z, 0.f);
      hv[3] = (bf16_t)fmaxf(acc1[it][jt][3] + bb.w, 0.f);
      *(bf16x4*)(hb + m * HB_STRIDE + n0) = hv;
    }
  }
  __syncthreads();

  // ---- GEMM2: y[m][d] = sum_h h[m][h] * W2T[d][h]; wave w owns d in [w*64, w*64+64)
  floatx4 acc2[4][4];
#pragma unroll
  for (int mt = 0; mt < 4; mt++)
#pragma unroll
    for (int dt = 0; dt < 4; dt++) {
      floatx4 z = {0.f, 0.f, 0.f, 0.f};
      acc2[mt][dt] = z;
    }

  const bf16_t* w2e = W2T + (size_t)e * DIM * HID;
#pragma unroll
  for (int k = 0; k < 16; k++) {
    bf16x8 afr[4];
#pragma unroll
    for (int mt = 0; mt < 4; mt++)
      afr[mt] = *(const bf16x8*)(hb + (mt * 16 + L15) * HB_STRIDE + k * 32 + quad * 8);
    bf16x8 bfr[4];
#pragma unroll
    for (int dt = 0; dt < 4; dt++) {
      int d = w * 64 + dt * 16 + L15;
      bfr[dt] = *(const bf16x8*)(w2e + d * HID + k * 32 + quad * 8);
    }
#pragma unroll
    for (int mt = 0; mt < 4; mt++)
#pragma unroll
      for (int dt = 0; dt < 4; dt++)
        acc2[mt][dt] = __builtin_amdgcn_mfma_f32_16x16x32_bf16(afr[mt], bfr[dt],
                                                               acc2[mt][dt], 0, 0, 0);
  }

  // epilogue 2: bias, gate-scale, scatter-add. Per (mt,dt,r) instr: 4 tokens x 16
  // consecutive d -> four fully-covered 64B lines per atomic instr.
#pragma unroll
  for (int mt = 0; mt < 4; mt++) {
#pragma unroll
    for (int r = 0; r < 4; r++) {
      int m = mt * 16 + quad * 4 + r;
      int t = tok_s[m];
      float sg = sc_s[m];
      float* orow = out + (size_t)t * DIM;
#pragma unroll
      for (int dt = 0; dt < 4; dt++) {
        int d = w * 64 + dt * 16 + L15;
        float v = (acc2[mt][dt][r] + b2s[d]) * sg;
        atomicAdd(orow + d, v);
      }
    }
  }
}

// ---------------- aux stats ----------------
__global__ void k_finalize(const int* __restrict__ cnt, const float* __restrict__ imp,
                           const float* __restrict__ ent, float* __restrict__ out) {
  if (threadIdx.x == 0 && blockIdx.x == 0) {
    double tot = 0.0;
    float disp[NE];
    for (int e = 0; e < NE; e++) {
      int c = min(cnt[e], CAP);
      disp[e] = (float)c;
      tot += (double)c;
    }
    double denom = tot > 0.0 ? tot : 1.0;
    double aux = 0.0;
    for (int e = 0; e < NE; e++)
      aux += ((double)imp[e] / (double)N_TOK) * ((double)disp[e] / denom);
    float* tail = out + (size_t)N_TOK * DIM;
    tail[0] = (float)(aux * (double)NE);
    tail[1] = (float)((double)ent[0] / (double)N_TOK);
    for (int e = 0; e < NE; e++) tail[2 + e] = disp[e];
  }
}

extern "C" void kernel_launch(void* const* d_in, const int* in_sizes, int n_in,
                              void* d_out, int out_size, void* d_ws, size_t ws_size,
                              hipStream_t stream) {
  const float* ctx = (const float*)d_in[0];
  const float* Wg = (const float*)d_in[1];
  const float* bg = (const float*)d_in[2];
  const float* W1 = (const float*)d_in[3];
  const float* b1 = (const float*)d_in[4];
  const float* W2 = (const float*)d_in[5];
  const float* b2 = (const float*)d_in[6];
  float* out = (float*)d_out;
  char* ws = (char*)d_ws;

  int* cnt = (int*)(ws + OFF_CNT);
  float* imp = (float*)(ws + OFF_IMP);
  float* ent = (float*)(ws + OFF_ENT);
  int* tok_list = (int*)(ws + OFF_TOK);
  float* sc_list = (float*)(ws + OFF_SC);
  bf16_t* W1T = (bf16_t*)(ws + OFF_W1T);
  bf16_t* W2T = (bf16_t*)(ws + OFF_W2T);

  k_zero<<<2048, 256, 0, stream>>>(out, cnt, imp, ent);
  k_transpose<<<dim3(HID / 32, DIM / 32, NE), dim3(32, 8), 0, stream>>>(W1, W1T, DIM, HID);
  k_transpose<<<dim3(DIM / 32, HID / 32, NE), dim3(32, 8), 0, stream>>>(W2, W2T, HID, DIM);
  k_router<<<N_TOK / 256, 256, 0, stream>>>(ctx, Wg, bg, cnt, tok_list, sc_list, imp, ent);
  // 16 experts x 282 chunks of 64 slots (ceil(18023/64)=282), xcd-swizzled: 8*564
  k_expert<<<4512, 256, 0, stream>>>(ctx, W1T, b1, W2T, b2, cnt, tok_list, sc_list, out);
  k_finalize<<<1, 64, 0, stream>>>(cnt, imp, ent, out);
}

// Round 2
// 701.666 us; speedup vs baseline: 2.3391x; 2.3391x over previous
//
#include <hip/hip_runtime.h>
#include <hip/hip_bf16.h>
#include <math.h>

#define N_TOK 131072
#define DIM 256
#define HID 512
#define NE 16
#define CAP 18023

typedef __bf16 bf16_t;
typedef __bf16 bf16x4 __attribute__((ext_vector_type(4)));
typedef __bf16 bf16x8 __attribute__((ext_vector_type(8)));
typedef float floatx4 __attribute__((ext_vector_type(4)));

// ---------------------------------------------------------------------------
// Workspace layout (bytes):
//   0       : int   cnt[16*16]   (one counter per 64B line: cnt[e*16])
//   1024    : float imp[16*16]   (importance sums, padded: imp[e*16])
//   2048    : float ent[1]
//   4096    : int   tok_list[16*CAP] (1153472 B)
//   1157568 : float sc_list[16*CAP]  (1153472 B)
//   2311168 : bf16  W1T[16][512][256] (4 MiB)   W1T[e][n][k] = W1[e][k][n]
//   6505472 : bf16  W2T[16][256][512] (4 MiB)   W2T[e][d][h] = W2[e][h][d]
// total ~10.2 MiB
// ---------------------------------------------------------------------------
#define OFF_CNT 0
#define OFF_IMP 1024
#define OFF_ENT 2048
#define OFF_TOK 4096
#define OFF_SC 1157568
#define OFF_W1T 2311168
#define OFF_W2T 6505472

// ---------------- zero output + stats ----------------
__global__ void k_zero(float* __restrict__ out, int* __restrict__ cnt,
                       float* __restrict__ imp, float* __restrict__ ent) {
  const int nthreads = 2048 * 256;  // grid is 2048 x 256
  int tid = blockIdx.x * 256 + threadIdx.x;
  float4* o4 = (float4*)out;
  float4 z = make_float4(0.f, 0.f, 0.f, 0.f);
#pragma unroll
  for (int j = 0; j < 16; j++) o4[(size_t)j * nthreads + tid] = z;  // 16*524288*4 = N*DIM
  if (blockIdx.x == 0) {
    if (threadIdx.x < NE) { cnt[threadIdx.x * 16] = 0; imp[threadIdx.x * 16] = 0.f; }
    if (threadIdx.x == NE) ent[0] = 0.f;
  }
}

// ---------------- per-expert weight transpose + bf16 cast ----------------
// src: [E][R][C] f32 -> dst: [E][C][R] bf16
__global__ void k_transpose(const float* __restrict__ src, bf16_t* __restrict__ dst,
                            int R, int C) {
  __shared__ float tile[32][33];
  int e = blockIdx.z;
  int c0 = blockIdx.x * 32;
  int r0 = blockIdx.y * 32;
  const float* s = src + (size_t)e * R * C;
  bf16_t* d = dst + (size_t)e * R * C;
  int tx = threadIdx.x, ty = threadIdx.y;  // block (32,8)
#pragma unroll
  for (int i = 0; i < 4; i++)
    tile[ty + i * 8][tx] = s[(size_t)(r0 + ty + i * 8) * C + (c0 + tx)];
  __syncthreads();
#pragma unroll
  for (int i = 0; i < 4; i++)
    d[(size_t)(c0 + ty + i * 8) * R + (r0 + tx)] = (bf16_t)tile[tx][ty + i * 8];
}

// ---------------- router: fp64 logits, top-2, gates, stats ----------------
// Atomics are hierarchical: LDS histogram -> 16 padded global atomics/block.
__launch_bounds__(256, 2)
__global__ void k_router(const float* __restrict__ ctx, const float* __restrict__ Wg,
                         const float* __restrict__ bg, int* __restrict__ cnt,
                         int* __restrict__ tok_list, float* __restrict__ sc_list,
                         float* __restrict__ imp, float* __restrict__ ent) {
  __shared__ double wg64[DIM * NE];  // 32 KiB, Wg in fp64
  __shared__ float xt[256 * 33];     // 33 KiB, 256 tokens x 32-dim chunk, stride 33 (bank-safe)
  __shared__ int lcnt[NE];           // block-local expert histogram
  __shared__ int lbase[NE];          // global base offsets for this block
  __shared__ float limp[NE];
  __shared__ float lent;
  const int tid = threadIdx.x;
  const int tok0 = blockIdx.x * 256;

  for (int i = 0; i < 16; i++) {
    int idx = i * 256 + tid;
    wg64[idx] = (double)Wg[idx];
  }
  if (tid < NE) { lcnt[tid] = 0; limp[tid] = 0.f; }
  if (tid == NE) lent = 0.f;

  double acc[NE];
#pragma unroll
  for (int e = 0; e < NE; e++) acc[e] = (double)bg[e];

  for (int c = 0; c < 8; c++) {
    __syncthreads();  // also orders wg64/lcnt init before use
    const float* src = ctx + (size_t)tok0 * DIM + c * 32;
#pragma unroll
    for (int i = 0; i < 8; i++) {
      int f = i * 256 + tid;  // float4 index within tile
      int row = f >> 3;
      int c4 = f & 7;
      float4 v = *(const float4*)(src + (size_t)row * DIM + c4 * 4);
      float* dstp = &xt[row * 33 + c4 * 4];
      dstp[0] = v.x; dstp[1] = v.y; dstp[2] = v.z; dstp[3] = v.w;
    }
    __syncthreads();
#pragma unroll
    for (int d = 0; d < 32; d++) {
      double x = (double)xt[tid * 33 + d];
      const double* wrow = &wg64[(c * 32 + d) * NE];
#pragma unroll
      for (int e = 0; e < NE; e++) acc[e] = fma(x, wrow[e], acc[e]);
    }
  }

  // top-2 (strict >: ties keep lowest index, matches lax.top_k)
  double v1 = -1e300, v2 = -1e300;
  int i1 = 0, i2 = 0;
#pragma unroll
  for (int e = 0; e < NE; e++) {
    double v = acc[e];
    if (v > v1) { v2 = v1; i2 = i1; v1 = v; i1 = e; }
    else if (v > v2) { v2 = v; i2 = e; }
  }

  // softmax probs (f32 ok: feeds only importance/entropy, 2% thresholds)
  float p[NE];
  float s = 0.f;
#pragma unroll
  for (int e = 0; e < NE; e++) { p[e] = expf((float)(acc[e] - v1)); s += p[e]; }
  float inv = 1.f / s;
  float entl = 0.f;
#pragma unroll
  for (int e = 0; e < NE; e++) {
    float pe = p[e] * inv; p[e] = pe;
    entl -= pe * logf(fmaxf(pe, 1e-9f));
  }

  // gate scores: softmax over top-2 values, fp64
  double rr = exp(v2 - v1);
  double den = 1.0 + rr;
  float g1 = (float)(1.0 / den);
  float g2 = (float)(rr / den);

  // ---- hierarchical slot assignment ----
  int p1 = atomicAdd(&lcnt[i1], 1);  // LDS atomics: block-local rank
  int p2 = atomicAdd(&lcnt[i2], 1);
  __syncthreads();
  if (tid < NE) lbase[tid] = atomicAdd(&cnt[tid * 16], lcnt[tid]);  // padded lines
  __syncthreads();

  int token = tok0 + tid;
  int pos = lbase[i1] + p1;
  if (pos < CAP) { tok_list[i1 * CAP + pos] = token; sc_list[i1 * CAP + pos] = g1; }
  pos = lbase[i2] + p2;
  if (pos < CAP) { tok_list[i2 * CAP + pos] = token; sc_list[i2 * CAP + pos] = g2; }

  // ---- stats: wave shuffle-reduce -> LDS -> one global atomic per expert/block ----
#pragma unroll
  for (int e = 0; e < NE; e++) {
    float v = p[e];
#pragma unroll
    for (int o = 32; o > 0; o >>= 1) v += __shfl_down(v, o);
    if ((tid & 63) == 0) atomicAdd(&limp[e], v);
  }
  {
    float v = entl;
#pragma unroll
    for (int o = 32; o > 0; o >>= 1) v += __shfl_down(v, o);
    if ((tid & 63) == 0) atomicAdd(&lent, v);
  }
  __syncthreads();
  if (tid < NE) atomicAdd(&imp[tid * 16], limp[tid]);
  if (tid == NE) atomicAdd(ent, lent);
}

// ---------------- fused 2-layer expert MLP, 64-slot tile, bf16 MFMA ----------------
#define XB_STRIDE 264  // 256 + 8 bf16 pad (16B) -> ~2-way LDS banks on b128 reads
#define HB_STRIDE 520  // 512 + 8

__launch_bounds__(256, 2)
__global__ void k_expert(const float* __restrict__ ctx,
                         const bf16_t* __restrict__ W1T, const float* __restrict__ b1,
                         const bf16_t* __restrict__ W2T, const float* __restrict__ b2,
                         const int* __restrict__ cnt,
                         const int* __restrict__ tok_list, const float* __restrict__ sc_list,
                         float* __restrict__ out) {
  // xb [64][264] bf16 (33792 B) aliases hb [64][520] bf16 (66560 B) — xb dead after GEMM1
  __shared__ __align__(16) char smem_raw[64 * HB_STRIDE * 2];
  __shared__ int tok_s[64];
  __shared__ float sc_s[64];
  __shared__ float b1s[HID];
  __shared__ float b2s[DIM];
  bf16_t* xb = (bf16_t*)smem_raw;
  bf16_t* hb = (bf16_t*)smem_raw;

  // XCD swizzle: bid%8 -> XCD; each XCD serves experts {2x, 2x+1} so its 1MB of
  // bf16 weights stays resident in that XCD's 4MB L2.
  const int bid = blockIdx.x;
  const int e = (bid & 7) * 2 + ((bid >> 3) & 1);
  const int chunk = bid >> 4;

  const int count = min(cnt[e * 16], CAP);
  const int m0 = chunk * 64;
  if (m0 >= count) return;  // uniform early-exit, before any barrier
  const int rem = min(64, count - m0);

  const int tid = threadIdx.x;
  const int lane = tid & 63;
  const int w = tid >> 6;       // wave 0..3
  const int L15 = lane & 15;
  const int quad = lane >> 4;

  if (tid < 64) {
    int t = 0; float sgate = 0.f;  // padded slots: token 0, gate 0 -> adds exact 0
    if (tid < rem) {
      t = tok_list[e * CAP + m0 + tid];
      sgate = sc_list[e * CAP + m0 + tid];
    }
    tok_s[tid] = t; sc_s[tid] = sgate;
  }
  for (int i = tid; i < HID; i += 256) b1s[i] = b1[e * HID + i];
  for (int i = tid; i < DIM; i += 256) b2s[i] = b2[e * DIM + i];
  __syncthreads();

  // gather x: one full 1KB context row per wave-instr (coalesced), cast bf16
#pragma unroll
  for (int i = 0; i < 16; i++) {
    int f = i * 256 + tid;
    int row = f >> 6;   // wave-uniform
    int c4 = f & 63;    // = lane
    float4 v = *(const float4*)(ctx + (size_t)tok_s[row] * DIM + c4 * 4);
    bf16x4 bv;
    bv[0] = (bf16_t)v.x; bv[1] = (bf16_t)v.y; bv[2] = (bf16_t)v.z; bv[3] = (bf16_t)v.w;
    *(bf16x4*)(xb + row * XB_STRIDE + c4 * 4) = bv;
  }
  __syncthreads();

  // ---- GEMM1': hT[n][m] = sum_k W1T[n][k] * x[m][k]; wave w owns n in [w*128, w*128+128)
  // A-frag = W1T rows (global, K-contig); B-frag = xb rows (LDS, K-contig).
  floatx4 acc1[8][4];
#pragma unroll
  for (int it = 0; it < 8; it++)
#pragma unroll
    for (int jt = 0; jt < 4; jt++) {
      floatx4 z = {0.f, 0.f, 0.f, 0.f};
      acc1[it][jt] = z;
    }

  const bf16_t* w1e = W1T + (size_t)e * HID * DIM;
#pragma unroll
  for (int k = 0; k < 8; k++) {
    bf16x8 afr[8];
#pragma unroll
    for (int it = 0; it < 8; it++) {
      int n = w * 128 + it * 16 + L15;
      afr[it] = *(const bf16x8*)(w1e + n * DIM + k * 32 + quad * 8);
    }
    bf16x8 bfr[4];
#pragma unroll
    for (int jt = 0; jt < 4; jt++) {
      int m = jt * 16 + L15;
      bfr[jt] = *(const bf16x8*)(xb + m * XB_STRIDE + k * 32 + quad * 8);
    }
#pragma unroll
    for (int it = 0; it < 8; it++)
#pragma unroll
      for (int jt = 0; jt < 4; jt++)
        acc1[it][jt] = __builtin_amdgcn_mfma_f32_16x16x32_bf16(afr[it], bfr[jt],
                                                               acc1[it][jt], 0, 0, 0);
  }
  __syncthreads();  // everyone done reading xb; hb may now overwrite it

  // epilogue 1: D[i=quad*4+r][j=L15] = hT[n0+r][m] -> h[m][n]; 4 consecutive n per
  // lane -> packed ds_write_b64 into hb[m][n] (A-operand-ready for GEMM2)
#pragma unroll
  for (int it = 0; it < 8; it++) {
    int n0 = w * 128 + it * 16 + quad * 4;
    float4 bb = *(const float4*)(&b1s[n0]);
#pragma unroll
    for (int jt = 0; jt < 4; jt++) {
      int m = jt * 16 + L15;
      bf16x4 hv;
      hv[0] = (bf16_t)fmaxf(acc1[it][jt][0] + bb.x, 0.f);
      hv[1] = (bf16_t)fmaxf(acc1[it][jt][1] + bb.y, 0.f);
      hv[2] = (bf16_t)fmaxf(acc1[it][jt][2] + bb.z, 0.f);
      hv[3] = (bf16_t)fmaxf(acc1[it][jt][3] + bb.w, 0.f);
      *(bf16x4*)(hb + m * HB_STRIDE + n0) = hv;
    }
  }
  __syncthreads();

  // ---- GEMM2: y[m][d] = sum_h h[m][h] * W2T[d][h]; wave w owns d in [w*64, w*64+64)
  floatx4 acc2[4][4];
#pragma unroll
  for (int mt = 0; mt < 4; mt++)
#pragma unroll
    for (int dt = 0; dt < 4; dt++) {
      floatx4 z = {0.f, 0.f, 0.f, 0.f};
      acc2[mt][dt] = z;
    }

  const bf16_t* w2e = W2T + (size_t)e * DIM * HID;
#pragma unroll
  for (int k = 0; k < 16; k++) {
    bf16x8 afr[4];
#pragma unroll
    for (int mt = 0; mt < 4; mt++)
      afr[mt] = *(const bf16x8*)(hb + (mt * 16 + L15) * HB_STRIDE + k * 32 + quad * 8);
    bf16x8 bfr[4];
#pragma unroll
    for (int dt = 0; dt < 4; dt++) {
      int d = w * 64 + dt * 16 + L15;
      bfr[dt] = *(const bf16x8*)(w2e + d * HID + k * 32 + quad * 8);
    }
#pragma unroll
    for (int mt = 0; mt < 4; mt++)
#pragma unroll
      for (int dt = 0; dt < 4; dt++)
        acc2[mt][dt] = __builtin_amdgcn_mfma_f32_16x16x32_bf16(afr[mt], bfr[dt],
                                                               acc2[mt][dt], 0, 0, 0);
  }

  // epilogue 2: bias, gate-scale, scatter-add. Per (mt,dt,r) instr: 4 tokens x 16
  // consecutive d -> four fully-covered 64B lines per atomic instr.
#pragma unroll
  for (int mt = 0; mt < 4; mt++) {
#pragma unroll
    for (int r = 0; r < 4; r++) {
      int m = mt * 16 + quad * 4 + r;
      int t = tok_s[m];
      float sg = sc_s[m];
      float* orow = out + (size_t)t * DIM;
#pragma unroll
      for (int dt = 0; dt < 4; dt++) {
        int d = w * 64 + dt * 16 + L15;
        float v = (acc2[mt][dt][r] + b2s[d]) * sg;
        atomicAdd(orow + d, v);
      }
    }
  }
}

// ---------------- aux stats ----------------
__global__ void k_finalize(const int* __restrict__ cnt, const float* __restrict__ imp,
                           const float* __restrict__ ent, float* __restrict__ out) {
  if (threadIdx.x == 0 && blockIdx.x == 0) {
    double tot = 0.0;
    float disp[NE];
    for (int e = 0; e < NE; e++) {
      int c = min(cnt[e * 16], CAP);
      disp[e] = (float)c;
      tot += (double)c;
    }
    double denom = tot > 0.0 ? tot : 1.0;
    double aux = 0.0;
    for (int e = 0; e < NE; e++)
      aux += ((double)imp[e * 16] / (double)N_TOK) * ((double)disp[e] / denom);
    float* tail = out + (size_t)N_TOK * DIM;
    tail[0] = (float)(aux * (double)NE);
    tail[1] = (float)((double)ent[0] / (double)N_TOK);
    for (int e = 0; e < NE; e++) tail[2 + e] = disp[e];
  }
}

extern "C" void kernel_launch(void* const* d_in, const int* in_sizes, int n_in,
                              void* d_out, int out_size, void* d_ws, size_t ws_size,
                              hipStream_t stream) {
  const float* ctx = (const float*)d_in[0];
  const float* Wg = (const float*)d_in[1];
  const float* bg = (const float*)d_in[2];
  const float* W1 = (const float*)d_in[3];
  const float* b1 = (const float*)d_in[4];
  const float* W2 = (const float*)d_in[5];
  const float* b2 = (const float*)d_in[6];
  float* out = (float*)d_out;
  char* ws = (char*)d_ws;

  int* cnt = (int*)(ws + OFF_CNT);
  float* imp = (float*)(ws + OFF_IMP);
  float* ent = (float*)(ws + OFF_ENT);
  int* tok_list = (int*)(ws + OFF_TOK);
  float* sc_list = (float*)(ws + OFF_SC);
  bf16_t* W1T = (bf16_t*)(ws + OFF_W1T);
  bf16_t* W2T = (bf16_t*)(ws + OFF_W2T);

  k_zero<<<2048, 256, 0, stream>>>(out, cnt, imp, ent);
  k_transpose<<<dim3(HID / 32, DIM / 32, NE), dim3(32, 8), 0, stream>>>(W1, W1T, DIM, HID);
  k_transpose<<<dim3(DIM / 32, HID / 32, NE), dim3(32, 8), 0, stream>>>(W2, W2T, HID, DIM);
  k_router<<<N_TOK / 256, 256, 0, stream>>>(ctx, Wg, bg, cnt, tok_list, sc_list, imp, ent);
  // 16 experts x 282 chunks of 64 slots (ceil(18023/64)=282), xcd-swizzled: 8*564
  k_expert<<<4512, 256, 0, stream>>>(ctx, W1T, b1, W2T, b2, cnt, tok_list, sc_list, out);
  k_finalize<<<1, 64, 0, stream>>>(cnt, imp, ent, out);
}

// Round 3
// 627.284 us; speedup vs baseline: 2.6165x; 1.1186x over previous
//
#include <hip/hip_runtime.h>
#include <hip/hip_bf16.h>
#include <math.h>

#define N_TOK 131072
#define DIM 256
#define HID 512
#define NE 16
#define CAP 18023

typedef __bf16 bf16_t;
typedef __bf16 bf16x4 __attribute__((ext_vector_type(4)));
typedef __bf16 bf16x8 __attribute__((ext_vector_type(8)));
typedef float floatx4 __attribute__((ext_vector_type(4)));
typedef double doublex4 __attribute__((ext_vector_type(4)));

// ---------------------------------------------------------------------------
// Workspace layout (bytes):
//   0        : int   cnt[16*16]   (one counter per 64B line: cnt[e*16])
//   1024     : float imp[16*16]   (padded: imp[e*16])
//   2048     : float ent[1]
//   4096     : int   tok_list[16*CAP] (1153472 B)
//   1157568  : float sc_list[16*CAP]  (1153472 B)
//   2311168  : bf16  W1T[16][512][256] (4 MiB)   W1T[e][n][k] = W1[e][k][n]
//   6505472  : bf16  W2T[16][256][512] (4 MiB)   W2T[e][d][h] = W2[e][h][d]
//   10699776 : int   inv[N][2]  (1 MiB)  slot id e*CAP+pos per pick, -1 if dropped
//   11748352 : bf16  y_buf[16][CAP][256] (147.6 MB)  gate-scaled expert outputs
// total ~152 MB. If ws_size is smaller, fall back to atomic combine.
// ---------------------------------------------------------------------------
#define OFF_CNT 0
#define OFF_IMP 1024
#define OFF_ENT 2048
#define OFF_TOK 4096
#define OFF_SC 1157568
#define OFF_W1T 2311168
#define OFF_W2T 6505472
#define OFF_INV 10699776
#define OFF_Y 11748352
#define WS_NEED (11748352UL + (size_t)NE * CAP * DIM * 2)

// ---------------- init stats (gather path: no output zeroing needed) ----------------
__global__ void k_init(int* __restrict__ cnt, float* __restrict__ imp,
                       float* __restrict__ ent) {
  if (threadIdx.x < NE) { cnt[threadIdx.x * 16] = 0; imp[threadIdx.x * 16] = 0.f; }
  if (threadIdx.x == NE) ent[0] = 0.f;
}

// ---------------- zero output (atomic-fallback path only) ----------------
__global__ void k_zero_out(float* __restrict__ out) {
  const int nthreads = 2048 * 256;
  int tid = blockIdx.x * 256 + threadIdx.x;
  float4* o4 = (float4*)out;
  float4 z = make_float4(0.f, 0.f, 0.f, 0.f);
#pragma unroll
  for (int j = 0; j < 16; j++) o4[(size_t)j * nthreads + tid] = z;
}

// ---------------- per-expert weight transpose + bf16 cast ----------------
// src: [E][R][C] f32 -> dst: [E][C][R] bf16
__global__ void k_transpose(const float* __restrict__ src, bf16_t* __restrict__ dst,
                            int R, int C) {
  __shared__ float tile[32][33];
  int e = blockIdx.z;
  int c0 = blockIdx.x * 32;
  int r0 = blockIdx.y * 32;
  const float* s = src + (size_t)e * R * C;
  bf16_t* d = dst + (size_t)e * R * C;
  int tx = threadIdx.x, ty = threadIdx.y;  // block (32,8)
#pragma unroll
  for (int i = 0; i < 4; i++)
    tile[ty + i * 8][tx] = s[(size_t)(r0 + ty + i * 8) * C + (c0 + tx)];
  __syncthreads();
#pragma unroll
  for (int i = 0; i < 4; i++)
    d[(size_t)(c0 + ty + i * 8) * R + (r0 + tx)] = (bf16_t)tile[tx][ty + i * 8];
}

// ---------------- router: fp64 logits, top-2, gates, stats, inverse map ----------------
__launch_bounds__(256, 2)
__global__ void k_router(const float* __restrict__ ctx, const float* __restrict__ Wg,
                         const float* __restrict__ bg, int* __restrict__ cnt,
                         int* __restrict__ tok_list, float* __restrict__ sc_list,
                         int* __restrict__ inv,
                         float* __restrict__ imp, float* __restrict__ ent) {
  __shared__ __align__(32) double wg64[DIM * NE];  // 32 KiB
  __shared__ float xt[256 * 33];  // 33 KiB, 256 tokens x 32-dim chunk, stride 33
  __shared__ int lcnt[NE];
  __shared__ int lbase[NE];
  __shared__ float limp[NE];
  __shared__ float lent;
  const int tid = threadIdx.x;
  const int tok0 = blockIdx.x * 256;

  for (int i = 0; i < 16; i++) {
    int idx = i * 256 + tid;
    wg64[idx] = (double)Wg[idx];
  }
  if (tid < NE) { lcnt[tid] = 0; limp[tid] = 0.f; }
  if (tid == NE) lent = 0.f;

  double acc[NE];
#pragma unroll
  for (int e = 0; e < NE; e++) acc[e] = (double)bg[e];

  for (int c = 0; c < 8; c++) {
    __syncthreads();  // also orders wg64/lcnt init before use
    const float* src = ctx + (size_t)tok0 * DIM + c * 32;
#pragma unroll
    for (int i = 0; i < 8; i++) {
      int f = i * 256 + tid;
      int row = f >> 3;
      int c4 = f & 7;
      float4 v = *(const float4*)(src + (size_t)row * DIM + c4 * 4);
      float* dstp = &xt[row * 33 + c4 * 4];
      dstp[0] = v.x; dstp[1] = v.y; dstp[2] = v.z; dstp[3] = v.w;
    }
    __syncthreads();
#pragma unroll
    for (int d = 0; d < 32; d++) {
      double x = (double)xt[tid * 33 + d];
      const double* wrow = &wg64[(c * 32 + d) * NE];
#pragma unroll
      for (int ee = 0; ee < 4; ee++) {  // double4 -> ds_read_b128 pairs
        doublex4 wv = *(const doublex4*)(wrow + ee * 4);
        acc[ee * 4 + 0] = fma(x, wv[0], acc[ee * 4 + 0]);
        acc[ee * 4 + 1] = fma(x, wv[1], acc[ee * 4 + 1]);
        acc[ee * 4 + 2] = fma(x, wv[2], acc[ee * 4 + 2]);
        acc[ee * 4 + 3] = fma(x, wv[3], acc[ee * 4 + 3]);
      }
    }
  }

  // top-2 (strict >: ties keep lowest index, matches lax.top_k)
  double v1 = -1e300, v2 = -1e300;
  int i1 = 0, i2 = 0;
#pragma unroll
  for (int e = 0; e < NE; e++) {
    double v = acc[e];
    if (v > v1) { v2 = v1; i2 = i1; v1 = v; i1 = e; }
    else if (v > v2) { v2 = v; i2 = e; }
  }

  // softmax probs (f32: feeds only importance/entropy)
  float p[NE];
  float s = 0.f;
#pragma unroll
  for (int e = 0; e < NE; e++) { p[e] = expf((float)(acc[e] - v1)); s += p[e]; }
  float inv_s = 1.f / s;
  float entl = 0.f;
#pragma unroll
  for (int e = 0; e < NE; e++) {
    float pe = p[e] * inv_s; p[e] = pe;
    entl -= pe * logf(fmaxf(pe, 1e-9f));
  }

  // gate scores: softmax over top-2 values, fp64
  double rr = exp(v2 - v1);
  double den = 1.0 + rr;
  float g1 = (float)(1.0 / den);
  float g2 = (float)(rr / den);

  // ---- hierarchical slot assignment ----
  int p1 = atomicAdd(&lcnt[i1], 1);  // LDS atomic: block-local rank
  int p2 = atomicAdd(&lcnt[i2], 1);
  __syncthreads();
  if (tid < NE) lbase[tid] = atomicAdd(&cnt[tid * 16], lcnt[tid]);  // padded lines
  __syncthreads();

  int token = tok0 + tid;
  int pos = lbase[i1] + p1;
  int l1 = -1;
  if (pos < CAP) { tok_list[i1 * CAP + pos] = token; sc_list[i1 * CAP + pos] = g1; l1 = i1 * CAP + pos; }
  pos = lbase[i2] + p2;
  int l2 = -1;
  if (pos < CAP) { tok_list[i2 * CAP + pos] = token; sc_list[i2 * CAP + pos] = g2; l2 = i2 * CAP + pos; }
  inv[token * 2] = l1;
  inv[token * 2 + 1] = l2;

  // ---- stats: wave shuffle-reduce -> LDS -> one global atomic per expert/block ----
#pragma unroll
  for (int e = 0; e < NE; e++) {
    float v = p[e];
#pragma unroll
    for (int o = 32; o > 0; o >>= 1) v += __shfl_down(v, o);
    if ((tid & 63) == 0) atomicAdd(&limp[e], v);
  }
  {
    float v = entl;
#pragma unroll
    for (int o = 32; o > 0; o >>= 1) v += __shfl_down(v, o);
    if ((tid & 63) == 0) atomicAdd(&lent, v);
  }
  __syncthreads();
  if (tid < NE) atomicAdd(&imp[tid * 16], limp[tid]);
  if (tid == NE) atomicAdd(ent, lent);
}

// ---------------- fused 2-layer expert MLP, 64-slot tile, bf16 MFMA ----------------
#define XB_STRIDE 264  // 256 + 8 bf16 pad
#define HB_STRIDE 520  // 512 + 8

template <bool GATHER>
__launch_bounds__(256, 2)
__global__ void k_expert(const float* __restrict__ ctx,
                         const bf16_t* __restrict__ W1T, const float* __restrict__ b1,
                         const bf16_t* __restrict__ W2T, const float* __restrict__ b2,
                         const int* __restrict__ cnt,
                         const int* __restrict__ tok_list, const float* __restrict__ sc_list,
                         bf16_t* __restrict__ y_buf, float* __restrict__ out) {
  // xb [64][264] bf16 aliases hb [64][520] bf16 aliases yb [64][264]
  __shared__ __align__(16) char smem_raw[64 * HB_STRIDE * 2];
  __shared__ int tok_s[64];
  __shared__ float sc_s[64];
  __shared__ float b1s[HID];
  __shared__ float b2s[DIM];
  bf16_t* xb = (bf16_t*)smem_raw;
  bf16_t* hb = (bf16_t*)smem_raw;
  bf16_t* yb = (bf16_t*)smem_raw;

  // XCD swizzle: bid%8 -> XCD; each XCD serves experts {2x,2x+1} -> 1MB weights/L2
  const int bid = blockIdx.x;
  const int e = (bid & 7) * 2 + ((bid >> 3) & 1);
  const int chunk = bid >> 4;

  const int count = min(cnt[e * 16], CAP);
  const int m0 = chunk * 64;
  if (m0 >= count) return;  // uniform early-exit, before any barrier
  const int rem = min(64, count - m0);

  const int tid = threadIdx.x;
  const int lane = tid & 63;
  const int w = tid >> 6;       // wave 0..3
  const int L15 = lane & 15;
  const int quad = lane >> 4;

  if (tid < 64) {
    int t = 0; float sgate = 0.f;  // padded slots: token 0, gate 0
    if (tid < rem) {
      t = tok_list[e * CAP + m0 + tid];
      sgate = sc_list[e * CAP + m0 + tid];
    }
    tok_s[tid] = t; sc_s[tid] = sgate;
  }
  for (int i = tid; i < HID; i += 256) b1s[i] = b1[e * HID + i];
  for (int i = tid; i < DIM; i += 256) b2s[i] = b2[e * DIM + i];
  __syncthreads();

  // gather x: one full 1KB context row per wave-instr (coalesced), cast bf16
#pragma unroll
  for (int i = 0; i < 16; i++) {
    int f = i * 256 + tid;
    int row = f >> 6;   // wave-uniform
    int c4 = f & 63;    // = lane
    float4 v = *(const float4*)(ctx + (size_t)tok_s[row] * DIM + c4 * 4);
    bf16x4 bv;
    bv[0] = (bf16_t)v.x; bv[1] = (bf16_t)v.y; bv[2] = (bf16_t)v.z; bv[3] = (bf16_t)v.w;
    *(bf16x4*)(xb + row * XB_STRIDE + c4 * 4) = bv;
  }
  __syncthreads();

  // ---- GEMM1': hT[n][m] = sum_k W1T[n][k]*x[m][k]; wave w owns n in [w*128, w*128+128)
  floatx4 acc1[8][4];
#pragma unroll
  for (int it = 0; it < 8; it++)
#pragma unroll
    for (int jt = 0; jt < 4; jt++) {
      floatx4 z = {0.f, 0.f, 0.f, 0.f};
      acc1[it][jt] = z;
    }

  const bf16_t* w1e = W1T + (size_t)e * HID * DIM;
#pragma unroll
  for (int k = 0; k < 8; k++) {
    bf16x8 afr[8];
#pragma unroll
    for (int it = 0; it < 8; it++) {
      int n = w * 128 + it * 16 + L15;
      afr[it] = *(const bf16x8*)(w1e + n * DIM + k * 32 + quad * 8);
    }
    bf16x8 bfr[4];
#pragma unroll
    for (int jt = 0; jt < 4; jt++) {
      int m = jt * 16 + L15;
      bfr[jt] = *(const bf16x8*)(xb + m * XB_STRIDE + k * 32 + quad * 8);
    }
#pragma unroll
    for (int it = 0; it < 8; it++)
#pragma unroll
      for (int jt = 0; jt < 4; jt++)
        acc1[it][jt] = __builtin_amdgcn_mfma_f32_16x16x32_bf16(afr[it], bfr[jt],
                                                               acc1[it][jt], 0, 0, 0);
  }
  __syncthreads();  // xb dead; hb may overwrite

  // epilogue 1: bias+relu, hT -> h[m][n] in LDS (A-operand-ready for GEMM2)
#pragma unroll
  for (int it = 0; it < 8; it++) {
    int n0 = w * 128 + it * 16 + quad * 4;
    float4 bb = *(const float4*)(&b1s[n0]);
#pragma unroll
    for (int jt = 0; jt < 4; jt++) {
      int m = jt * 16 + L15;
      bf16x4 hv;
      hv[0] = (bf16_t)fmaxf(acc1[it][jt][0] + bb.x, 0.f);
      hv[1] = (bf16_t)fmaxf(acc1[it][jt][1] + bb.y, 0.f);
      hv[2] = (bf16_t)fmaxf(acc1[it][jt][2] + bb.z, 0.f);
      hv[3] = (bf16_t)fmaxf(acc1[it][jt][3] + bb.w, 0.f);
      *(bf16x4*)(hb + m * HB_STRIDE + n0) = hv;
    }
  }
  __syncthreads();

  // ---- GEMM2: y[m][d] = sum_h h[m][h]*W2T[d][h]; wave w owns d in [w*64, w*64+64)
  floatx4 acc2[4][4];
#pragma unroll
  for (int mt = 0; mt < 4; mt++)
#pragma unroll
    for (int dt = 0; dt < 4; dt++) {
      floatx4 z = {0.f, 0.f, 0.f, 0.f};
      acc2[mt][dt] = z;
    }

  const bf16_t* w2e = W2T + (size_t)e * DIM * HID;
#pragma unroll
  for (int k = 0; k < 16; k++) {
    bf16x8 afr[4];
#pragma unroll
    for (int mt = 0; mt < 4; mt++)
      afr[mt] = *(const bf16x8*)(hb + (mt * 16 + L15) * HB_STRIDE + k * 32 + quad * 8);
    bf16x8 bfr[4];
#pragma unroll
    for (int dt = 0; dt < 4; dt++) {
      int d = w * 64 + dt * 16 + L15;
      bfr[dt] = *(const bf16x8*)(w2e + d * HID + k * 32 + quad * 8);
    }
#pragma unroll
    for (int mt = 0; mt < 4; mt++)
#pragma unroll
      for (int dt = 0; dt < 4; dt++)
        acc2[mt][dt] = __builtin_amdgcn_mfma_f32_16x16x32_bf16(afr[mt], bfr[dt],
                                                               acc2[mt][dt], 0, 0, 0);
  }

  if (GATHER) {
    // epilogue 2a: bias + gate-scale -> bf16 yb[m][d] in LDS, then coalesced
    // 512B row stores into y_buf (no atomics; combine kernel gathers later).
    __syncthreads();  // hb reads done; yb aliases
#pragma unroll
    for (int mt = 0; mt < 4; mt++) {
#pragma unroll
      for (int r = 0; r < 4; r++) {
        int m = mt * 16 + quad * 4 + r;
        float sg = sc_s[m];
#pragma unroll
        for (int dt = 0; dt < 4; dt++) {
          int d = w * 64 + dt * 16 + L15;
          yb[m * XB_STRIDE + d] = (bf16_t)((acc2[mt][dt][r] + b2s[d]) * sg);
        }
      }
    }
    __syncthreads();
    bf16_t* ybase = y_buf + ((size_t)e * CAP + m0) * DIM;
#pragma unroll
    for (int i = 0; i < 16; i++) {
      int row = i * 4 + w;  // wave-uniform
      if (row < rem) {      // never write past count -> no cross-expert clobber
        bf16x4 v = *(const bf16x4*)(yb + row * XB_STRIDE + lane * 4);
        *(bf16x4*)(ybase + (size_t)row * DIM + lane * 4) = v;
      }
    }
  } else {
    // epilogue 2b (fallback): atomic scatter-add
#pragma unroll
    for (int mt = 0; mt < 4; mt++) {
#pragma unroll
      for (int r = 0; r < 4; r++) {
        int m = mt * 16 + quad * 4 + r;
        int t = tok_s[m];
        float sg = sc_s[m];
        float* orow = out + (size_t)t * DIM;
#pragma unroll
        for (int dt = 0; dt < 4; dt++) {
          int d = w * 64 + dt * 16 + L15;
          float v = (acc2[mt][dt][r] + b2s[d]) * sg;
          atomicAdd(orow + d, v);
        }
      }
    }
  }
}

// ---------------- combine: per token, gather 2 slot rows, sum, write ----------------
__global__ void k_combine(const bf16_t* __restrict__ y_buf, const int* __restrict__ inv,
                          float* __restrict__ out) {
  __shared__ int loc_s[128];
  const int tid = threadIdx.x;
  const int tok0 = blockIdx.x * 64;
  if (tid < 128) loc_s[tid] = inv[tok0 * 2 + tid];
  __syncthreads();
  const int w = tid >> 6;
  const int lane = tid & 63;
#pragma unroll
  for (int i = 0; i < 16; i++) {
    int row = i * 4 + w;  // wave-uniform
    int l1 = loc_s[row * 2];
    int l2 = loc_s[row * 2 + 1];
    float4 o = make_float4(0.f, 0.f, 0.f, 0.f);
    if (l1 >= 0) {
      bf16x4 a = *(const bf16x4*)(y_buf + (size_t)l1 * DIM + lane * 4);
      o.x += (float)a[0]; o.y += (float)a[1]; o.z += (float)a[2]; o.w += (float)a[3];
    }
    if (l2 >= 0) {
      bf16x4 b = *(const bf16x4*)(y_buf + (size_t)l2 * DIM + lane * 4);
      o.x += (float)b[0]; o.y += (float)b[1]; o.z += (float)b[2]; o.w += (float)b[3];
    }
    *(float4*)(out + (size_t)(tok0 + row) * DIM + lane * 4) = o;
  }
}

// ---------------- aux stats ----------------
__global__ void k_finalize(const int* __restrict__ cnt, const float* __restrict__ imp,
                           const float* __restrict__ ent, float* __restrict__ out) {
  if (threadIdx.x == 0 && blockIdx.x == 0) {
    double tot = 0.0;
    float disp[NE];
    for (int e = 0; e < NE; e++) {
      int c = min(cnt[e * 16], CAP);
      disp[e] = (float)c;
      tot += (double)c;
    }
    double denom = tot > 0.0 ? tot : 1.0;
    double aux = 0.0;
    for (int e = 0; e < NE; e++)
      aux += ((double)imp[e * 16] / (double)N_TOK) * ((double)disp[e] / denom);
    float* tail = out + (size_t)N_TOK * DIM;
    tail[0] = (float)(aux * (double)NE);
    tail[1] = (float)((double)ent[0] / (double)N_TOK);
    for (int e = 0; e < NE; e++) tail[2 + e] = disp[e];
  }
}

extern "C" void kernel_launch(void* const* d_in, const int* in_sizes, int n_in,
                              void* d_out, int out_size, void* d_ws, size_t ws_size,
                              hipStream_t stream) {
  const float* ctx = (const float*)d_in[0];
  const float* Wg = (const float*)d_in[1];
  const float* bg = (const float*)d_in[2];
  const float* W1 = (const float*)d_in[3];
  const float* b1 = (const float*)d_in[4];
  const float* W2 = (const float*)d_in[5];
  const float* b2 = (const float*)d_in[6];
  float* out = (float*)d_out;
  char* ws = (char*)d_ws;

  int* cnt = (int*)(ws + OFF_CNT);
  float* imp = (float*)(ws + OFF_IMP);
  float* ent = (float*)(ws + OFF_ENT);
  int* tok_list = (int*)(ws + OFF_TOK);
  float* sc_list = (float*)(ws + OFF_SC);
  bf16_t* W1T = (bf16_t*)(ws + OFF_W1T);
  bf16_t* W2T = (bf16_t*)(ws + OFF_W2T);
  int* inv = (int*)(ws + OFF_INV);
  bf16_t* y_buf = (bf16_t*)(ws + OFF_Y);

  const bool gather = ws_size >= WS_NEED;  // constant across calls: graph-safe

  k_init<<<1, 64, 0, stream>>>(cnt, imp, ent);
  if (!gather) k_zero_out<<<2048, 256, 0, stream>>>(out);
  k_transpose<<<dim3(HID / 32, DIM / 32, NE), dim3(32, 8), 0, stream>>>(W1, W1T, DIM, HID);
  k_transpose<<<dim3(DIM / 32, HID / 32, NE), dim3(32, 8), 0, stream>>>(W2, W2T, HID, DIM);
  k_router<<<N_TOK / 256, 256, 0, stream>>>(ctx, Wg, bg, cnt, tok_list, sc_list, inv, imp, ent);
  // 16 experts x 282 chunks of 64 slots, xcd-swizzled
  if (gather) {
    k_expert<true><<<4512, 256, 0, stream>>>(ctx, W1T, b1, W2T, b2, cnt, tok_list, sc_list,
                                             y_buf, out);
    k_combine<<<N_TOK / 64, 256, 0, stream>>>(y_buf, inv, out);
  } else {
    k_expert<false><<<4512, 256, 0, stream>>>(ctx, W1T, b1, W2T, b2, cnt, tok_list, sc_list,
                                              y_buf, out);
  }
  k_finalize<<<1, 64, 0, stream>>>(cnt, imp, ent, out);
}